// Round 3
// baseline (16057.385 us; speedup 1.0000x reference)
//
#include <hip/hip_runtime.h>
#include <hip/hip_cooperative_groups.h>

namespace cg = cooperative_groups;

#define BATCHES 16
#define NG 2048
#define FDIM 1024
#define EPG 65536
#define NTOT (BATCHES*NG)      // 32768
#define ETOT (BATCHES*EPG)     // 1048576
#define STEPS 64
#define NBLK 512
#define NTHR 256
#define BLK_PER_BATCH (NBLK/BATCHES)          // 32
#define ROWS_PER_BLK (NG/BLK_PER_BATCH)       // 64
#define EDGE_PER_BLK (ETOT/NBLK)              // 2048

__device__ __forceinline__ double block_reduce_sum(double v, double* s_red) {
    for (int off = 32; off > 0; off >>= 1)
        v += __shfl_down(v, off, 64);
    __syncthreads();                 // protect s_red reuse across calls
    int lane = threadIdx.x & 63;
    int wave = threadIdx.x >> 6;
    if (lane == 0) s_red[wave] = v;
    __syncthreads();
    return (s_red[0] + s_red[1]) + (s_red[2] + s_red[3]);
}

__global__ __launch_bounds__(NTHR, 2)
void GradSolver_58102317580919_kernel(
    const float* __restrict__ x_start,
    const float* __restrict__ rhs,
    const float* __restrict__ proj,
    const float* __restrict__ q,
    const float* __restrict__ obj_solution,
    const int*   __restrict__ edge_index,   // [2, ETOT] int32
    const float* __restrict__ edge_weight,
    float* __restrict__ out,                // [NTOT bestx][B best][B*STEPS gaps]
    void* __restrict__ wsv)
{
    cg::grid_group grid = cg::this_grid();

    double* xb0  = (double*)wsv;         // N
    double* xb1  = xb0 + NTOT;           // N
    double* pred = xb1 + NTOT;           // N
    double* coef = pred + NTOT;          // B*F
    double* quad = coef + BATCHES*FDIM;  // B
    double* lin  = quad + BATCHES;       // B
    unsigned long long* minr = (unsigned long long*)(lin + BATCHES); // B

    const int tid   = threadIdx.x;
    const int bid   = blockIdx.x;
    const int batch = bid / BLK_PER_BATCH;
    const int n0    = (bid % BLK_PER_BATCH) * ROWS_PER_BLK;
    const int row_base = batch * NG + n0;

    const unsigned long long DINF = 0x7FF0000000000000ULL;

    __shared__ double s_d[ROWS_PER_BLK];
    __shared__ double s_coef[FDIM];
    __shared__ double s_red[4];
    __shared__ double s_bestobj;

    // ---------------- P0: init ----------------
    if (tid < ROWS_PER_BLK) {
        int gr = row_base + tid;
        xb0[gr] = (double)x_start[gr];
    }
    {   // zero coef: 16384 doubles / 512 blocks = 32 each
        const int per = (BATCHES*FDIM)/NBLK;
        if (tid < per) coef[bid*per + tid] = 0.0;
    }
    if (bid == 0 && tid < BATCHES) { quad[tid] = 0.0; lin[tid] = 0.0; minr[tid] = DINF; }
    if (tid == 0) s_bestobj = __longlong_as_double((long long)DINF); // +inf
    double tau = 1.0;
    grid.sync();

    // ---------------- P1: obj(x_start) ----------------
    {
        double lp = 0.0;
        if (tid < ROWS_PER_BLK) {
            int gr = row_base + tid;
            lp = (double)q[gr] * xb0[gr];
        }
        double ls = block_reduce_sum(lp, s_red);
        if (tid == 0) unsafeAtomicAdd(&lin[batch], ls);

        const int e0 = bid * EDGE_PER_BLK;
        double qp = 0.0;
        #pragma unroll 4
        for (int j = 0; j < EDGE_PER_BLK/NTHR; ++j) {
            int e  = e0 + tid + j*NTHR;
            int si = edge_index[e];
            int di = edge_index[ETOT + e];
            qp += (double)edge_weight[e] * xb0[si] * xb0[di];
        }
        double qs = block_reduce_sum(qp, s_red);
        if (tid == 0) unsafeAtomicAdd(&quad[batch], qs);
    }
    grid.sync();

    // ---------------- main loop ----------------
    for (int k = 0; k <= STEPS; ++k) {
        // ---- Phase A: finalize prev obj, direction, coef ----
        double cur = 0.5 * quad[batch] + lin[batch];
        double bo  = s_bestobj;
        bool better = cur < bo;
        double nb  = better ? cur : bo;
        __syncthreads();                 // everyone read s_bestobj
        if (tid == 0) s_bestobj = nb;

        if (k > 0 && (bid % BLK_PER_BATCH) == 0 && tid == 0) {
            double opt = (double)obj_solution[batch];
            out[NTOT + BATCHES + batch*STEPS + (k-1)] = (float)fabs((opt - nb)/opt);
        }

        double* xc = (k & 1) ? xb1 : xb0;
        double* xn = (k & 1) ? xb0 : xb1;

        if (better && tid < ROWS_PER_BLK) {
            int gr = row_base + tid;
            out[gr] = (float)xc[gr];     // best_x
        }
        if (k == STEPS) {
            if ((bid % BLK_PER_BATCH) == 0 && tid == 0) {
                double opt = (double)obj_solution[batch];
                out[NTOT + batch] = (float)fabs((opt - nb)/opt);   // best
            }
            break;
        }

        if (bid == 0 && tid < BATCHES) minr[tid] = DINF;  // reset for B

        if (tid < ROWS_PER_BLK) {
            int gr = row_base + tid;
            double xv = xc[gr];
            s_d[tid] = -xv + (double)rhs[gr] + 0.1 * tau / (xv + tau);
        }
        tau = fmax(tau * 0.5, 1e-5);
        __syncthreads();

        {   // coef accumulation: thread t owns f = 4t..4t+3
            double a0 = 0.0, a1 = 0.0, a2 = 0.0, a3 = 0.0;
            const float4* P4 = (const float4*)(proj + (size_t)row_base * FDIM);
            #pragma unroll 8
            for (int r = 0; r < ROWS_PER_BLK; ++r) {
                float4 p = P4[r*(FDIM/4) + tid];
                double dv = s_d[r];
                a0 += (double)p.x*dv; a1 += (double)p.y*dv;
                a2 += (double)p.z*dv; a3 += (double)p.w*dv;
            }
            double* cf = coef + batch*FDIM + 4*tid;
            unsafeAtomicAdd(cf+0, a0); unsafeAtomicAdd(cf+1, a1);
            unsafeAtomicAdd(cf+2, a2); unsafeAtomicAdd(cf+3, a3);
        }
        grid.sync();

        // ---- Phase B: pred rows + min ratio ----
        if (bid == 0 && tid < BATCHES) { quad[tid] = 0.0; lin[tid] = 0.0; }
        {
            const double2* g2 = (const double2*)(coef + batch*FDIM);
            ((double2*)s_coef)[tid]       = g2[tid];
            ((double2*)s_coef)[tid + 256] = g2[tid + 256];
        }
        __syncthreads();

        {
            const int wave = tid >> 6, lane = tid & 63;
            // hoist this lane's coef slice (features 4*(lane+64j)..+3, j=0..3)
            double c[16];
            #pragma unroll
            for (int j = 0; j < 4; ++j) {
                int f = 4*(lane + 64*j);
                c[4*j+0] = s_coef[f+0]; c[4*j+1] = s_coef[f+1];
                c[4*j+2] = s_coef[f+2]; c[4*j+3] = s_coef[f+3];
            }
            double wmin = 1e300;
            for (int i = 0; i < ROWS_PER_BLK/4; ++i) {   // 16 rows per wave
                int r  = wave * (ROWS_PER_BLK/4) + i;
                int gr = row_base + r;
                const float4* Pr = (const float4*)(proj + (size_t)gr * FDIM);
                double dot = 0.0;
                #pragma unroll
                for (int j = 0; j < 4; ++j) {
                    float4 p = Pr[lane + 64*j];
                    dot += (double)p.x*c[4*j+0] + (double)p.y*c[4*j+1]
                         + (double)p.z*c[4*j+2] + (double)p.w*c[4*j+3];
                }
                for (int off = 32; off > 0; off >>= 1)
                    dot += __shfl_down(dot, off, 64);
                if (lane == 0) {
                    pred[gr] = dot;
                    if (dot < 0.0) wmin = fmin(wmin, xc[gr] / (-dot));
                }
            }
            if (lane == 0)
                atomicMin(&minr[batch], (unsigned long long)__double_as_longlong(wmin));
        }
        grid.sync();

        // ---- Phase C: x update + lin + edge quad ----
        {   // zero coef for next iter
            const int per = (BATCHES*FDIM)/NBLK;
            if (tid < per) coef[bid*per + tid] = 0.0;
        }
        double alpha = fmin(__longlong_as_double((long long)minr[batch]), 1.0) * 0.995;

        double lp = 0.0;
        if (tid < ROWS_PER_BLK) {
            int gr = row_base + tid;
            double xv = xc[gr] + alpha * pred[gr];
            xn[gr] = xv;
            lp = (double)q[gr] * xv;
        }
        double ls = block_reduce_sum(lp, s_red);
        if (tid == 0) unsafeAtomicAdd(&lin[batch], ls);

        {
            const int e0 = bid * EDGE_PER_BLK;
            double qp = 0.0;
            #pragma unroll 4
            for (int j = 0; j < EDGE_PER_BLK/NTHR; ++j) {
                int e  = e0 + tid + j*NTHR;
                int si = edge_index[e];
                int di = edge_index[ETOT + e];
                double xs = xc[si] + alpha * pred[si];
                double xd = xc[di] + alpha * pred[di];
                qp += (double)edge_weight[e] * xs * xd;
            }
            double qs = block_reduce_sum(qp, s_red);
            if (tid == 0) unsafeAtomicAdd(&quad[batch], qs);
        }
        grid.sync();
    }
}

extern "C" void kernel_launch(void* const* d_in, const int* in_sizes, int n_in,
                              void* d_out, int out_size, void* d_ws, size_t ws_size,
                              hipStream_t stream) {
    const float* x_start      = (const float*)d_in[0];
    const float* rhs          = (const float*)d_in[1];
    const float* proj         = (const float*)d_in[2];
    const float* q            = (const float*)d_in[3];
    const float* obj_solution = (const float*)d_in[4];
    const int*   edge_index   = (const int*)d_in[5];
    const float* edge_weight  = (const float*)d_in[6];
    // d_in[7] = vals_batch (derivable: batch = index / 2048) — unused
    float* out = (float*)d_out;
    void* ws   = d_ws;

    void* args[] = { (void*)&x_start, (void*)&rhs, (void*)&proj, (void*)&q,
                     (void*)&obj_solution, (void*)&edge_index, (void*)&edge_weight,
                     (void*)&out, (void*)&ws };
    hipLaunchCooperativeKernel((void*)GradSolver_58102317580919_kernel,
                               dim3(NBLK), dim3(NTHR), args, 0, stream);
}

// Round 4
// 7976.045 us; speedup vs baseline: 2.0132x; 2.0132x over previous
//
#include <hip/hip_runtime.h>

#define BATCHES 16
#define NG 2048
#define FDIM 1024
#define EPG 65536
#define NTOT (BATCHES*NG)      // 32768
#define ETOT (BATCHES*EPG)     // 1048576
#define STEPS 64
#define NBLK 512
#define NTHR 256
#define BLK_PER_BATCH (NBLK/BATCHES)          // 32
#define ROWS_PER_BLK (NG/BLK_PER_BATCH)       // 64
#define EDGE_PER_BLK (ETOT/NBLK)              // 2048

// ws layout (double-sized slots):
// [0)        xb0[NTOT]
// [NTOT)     xb1[NTOT]
// [2N)       pred[NTOT]
// [3N)       coef[2][BATCHES*FDIM]
// ...        quad[2][16], lin[2][16], minr(u64)[2][16], barrier(u64)[2]
#define WS_XB0   0
#define WS_XB1   (NTOT)
#define WS_PRED  (2*NTOT)
#define WS_COEF  (3*NTOT)
#define WS_QUAD  (3*NTOT + 2*BATCHES*FDIM)
#define WS_LIN   (WS_QUAD + 2*BATCHES)
#define WS_MINR  (WS_LIN + 2*BATCHES)          // u64 cells
#define WS_BAR   (WS_MINR + 2*BATCHES)         // u64 cells: [arrive, gen]

__device__ __forceinline__ double ld_ag(const double* p) {
    return __hip_atomic_load(p, __ATOMIC_RELAXED, __HIP_MEMORY_SCOPE_AGENT);
}
__device__ __forceinline__ void st_ag(double* p, double v) {
    __hip_atomic_store(p, v, __ATOMIC_RELAXED, __HIP_MEMORY_SCOPE_AGENT);
}
__device__ __forceinline__ unsigned long long ldu64_ag(const unsigned long long* p) {
    return __hip_atomic_load(p, __ATOMIC_RELAXED, __HIP_MEMORY_SCOPE_AGENT);
}
__device__ __forceinline__ void stu64_ag(unsigned long long* p, unsigned long long v) {
    __hip_atomic_store(p, v, __ATOMIC_RELAXED, __HIP_MEMORY_SCOPE_AGENT);
}

// Lean grid barrier: no L2 writeback/invalidate. All cross-block data uses
// the coherent (LLC) path, so only completion ordering is needed.
__device__ __forceinline__ void grid_barrier(unsigned long long* bar,
                                             unsigned long long g, int tid) {
    asm volatile("s_waitcnt vmcnt(0)" ::: "memory");  // all my LLC-path ops performed
    __syncthreads();
    if (tid == 0) {
        unsigned long long old = __hip_atomic_fetch_add(
            &bar[0], 1ULL, __ATOMIC_RELAXED, __HIP_MEMORY_SCOPE_AGENT);
        if (old == (unsigned long long)NBLK * g - 1ULL) {
            stu64_ag(&bar[1], g);
        } else {
            while (ldu64_ag(&bar[1]) < g) __builtin_amdgcn_s_sleep(2);
        }
    }
    __syncthreads();
}

__device__ __forceinline__ double block_reduce_sum(double v, double* s_red) {
    for (int off = 32; off > 0; off >>= 1)
        v += __shfl_down(v, off, 64);
    __syncthreads();
    int lane = threadIdx.x & 63;
    int wave = threadIdx.x >> 6;
    if (lane == 0) s_red[wave] = v;
    __syncthreads();
    return (s_red[0] + s_red[1]) + (s_red[2] + s_red[3]);
}

__global__ __launch_bounds__(NTHR, 2)
void GradSolver_58102317580919_kernel(
    const float* __restrict__ x_start,
    const float* __restrict__ rhs,
    const float* __restrict__ proj,
    const float* __restrict__ q,
    const float* __restrict__ obj_solution,
    const int*   __restrict__ edge_index,
    const float* __restrict__ edge_weight,
    float* __restrict__ out,                // [NTOT bestx][B best][B*STEPS gaps]
    void* __restrict__ wsv)
{
    double* ws = (double*)wsv;
    double* xb[2] = { ws + WS_XB0, ws + WS_XB1 };
    double* pred  = ws + WS_PRED;
    double* coef  = ws + WS_COEF;                    // [2][B*F]
    double* quad  = ws + WS_QUAD;                    // [2][16]
    double* lin   = ws + WS_LIN;                     // [2][16]
    unsigned long long* minr = (unsigned long long*)(ws + WS_MINR); // [2][16]
    unsigned long long* bar  = (unsigned long long*)(ws + WS_BAR);

    const int tid   = threadIdx.x;
    const int bid   = blockIdx.x;
    const int batch = bid / BLK_PER_BATCH;
    const int row_base = batch * NG + (bid % BLK_PER_BATCH) * ROWS_PER_BLK;

    const unsigned long long DINF = 0x7FF0000000000000ULL;

    __shared__ double s_d[ROWS_PER_BLK];
    __shared__ double s_x[ROWS_PER_BLK];
    __shared__ double s_pred[ROWS_PER_BLK];
    __shared__ double s_coef[FDIM];
    __shared__ double s_red[4];
    __shared__ double s_bestobj;

    unsigned long long g = 0;
    double tau = 1.0;

    // ---- P0: zero accumulators (LLC path; barrier region pre-zeroed by memset) ----
    if (tid < 64) st_ag(&coef[bid*64 + tid], 0.0);   // 2*16384 / 512 = 64 each
    if (bid == 0 && tid < 16) {
        st_ag(&quad[tid], 0.0);      st_ag(&quad[16+tid], 0.0);
        st_ag(&lin[tid],  0.0);      st_ag(&lin[16+tid],  0.0);
        stu64_ag(&minr[tid], DINF);  stu64_ag(&minr[16+tid], DINF);
    }
    if (tid == 0) s_bestobj = __longlong_as_double((long long)DINF);
    grid_barrier(bar, ++g, tid);

    for (int k = 0; k <= STEPS; ++k) {
        const int p  = k & 1;        // this step's accumulation parity
        const int pp = 1 - p;        // previous step's parity
        // ================= Phase CA =================
        double alpha = 0.0;
        if (k > 0) {
            unsigned long long m = ldu64_ag(&minr[pp*16 + batch]);
            alpha = fmin(__longlong_as_double((long long)m), 1.0) * 0.995;
        }
        double xv = 0.0;
        if (tid < ROWS_PER_BLK) {
            xv = (k == 0) ? (double)x_start[row_base + tid]
                          : s_x[tid] + alpha * s_pred[tid];
            s_x[tid] = xv;
            st_ag(&xb[p][row_base + tid], xv);
            if (k < STEPS)
                s_d[tid] = -xv + (double)rhs[row_base + tid] + 0.1 * tau / (xv + tau);
        }
        tau = fmax(tau * 0.5, 1e-5);
        // resets (all barrier-separated from their readers/writers):
        if (k >= 1 && tid < 32) st_ag(&coef[pp*(BATCHES*FDIM) + bid*32 + tid], 0.0);
        if (k < STEPS && bid == 0 && tid < 16) stu64_ag(&minr[p*16 + tid], DINF);

        // lin += q . x_k
        double lp = (tid < ROWS_PER_BLK) ? (double)q[row_base + tid] * xv : 0.0;
        double ls = block_reduce_sum(lp, s_red);
        if (tid == 0) unsafeAtomicAdd(&lin[p*16 + batch], ls);

        // quad += w * x_k[s] * x_k[d]  (x_k reconstructed from stale x/pred)
        {
            const int e0 = bid * EDGE_PER_BLK;
            double qp = 0.0;
            if (k == 0) {
                #pragma unroll 4
                for (int j = 0; j < EDGE_PER_BLK/NTHR; ++j) {
                    int e  = e0 + tid + j*NTHR;
                    int si = edge_index[e];
                    int di = edge_index[ETOT + e];
                    qp += (double)edge_weight[e] * (double)x_start[si] * (double)x_start[di];
                }
            } else {
                const double* xprev = xb[pp];
                #pragma unroll 4
                for (int j = 0; j < EDGE_PER_BLK/NTHR; ++j) {
                    int e  = e0 + tid + j*NTHR;
                    int si = edge_index[e];
                    int di = edge_index[ETOT + e];
                    double xs = ld_ag(&xprev[si]) + alpha * ld_ag(&pred[si]);
                    double xd = ld_ag(&xprev[di]) + alpha * ld_ag(&pred[di]);
                    qp += (double)edge_weight[e] * xs * xd;
                }
            }
            double qs = block_reduce_sum(qp, s_red);
            if (tid == 0) unsafeAtomicAdd(&quad[p*16 + batch], qs);
        }

        // coef += P^T d   (block-own rows only — no sync needed beyond LDS)
        if (k < STEPS) {
            __syncthreads();   // s_d complete
            double a0 = 0.0, a1 = 0.0, a2 = 0.0, a3 = 0.0;
            const float4* P4 = (const float4*)(proj + (size_t)row_base * FDIM);
            #pragma unroll 8
            for (int r = 0; r < ROWS_PER_BLK; ++r) {
                float4 pv = P4[r*(FDIM/4) + tid];
                double dv = s_d[r];
                a0 += (double)pv.x*dv; a1 += (double)pv.y*dv;
                a2 += (double)pv.z*dv; a3 += (double)pv.w*dv;
            }
            double* cf = coef + p*(BATCHES*FDIM) + batch*FDIM + 4*tid;
            unsafeAtomicAdd(cf+0, a0); unsafeAtomicAdd(cf+1, a1);
            unsafeAtomicAdd(cf+2, a2); unsafeAtomicAdd(cf+3, a3);
        }
        grid_barrier(bar, ++g, tid);

        // ================= Phase B =================
        double cur = 0.5 * ld_ag(&quad[p*16 + batch]) + ld_ag(&lin[p*16 + batch]);
        double bo  = s_bestobj;
        bool better = cur < bo;
        double nb  = better ? cur : bo;
        __syncthreads();
        if (tid == 0) s_bestobj = nb;

        if ((bid % BLK_PER_BATCH) == 0 && tid == 0) {
            double opt = (double)obj_solution[batch];
            double gap = fabs((opt - nb)/opt);
            if (k >= 1)     out[NTOT + BATCHES + batch*STEPS + (k-1)] = (float)gap;
            if (k == STEPS) out[NTOT + batch] = (float)gap;
        }
        if (better && tid < ROWS_PER_BLK)
            out[row_base + tid] = (float)s_x[tid];

        if (k == STEPS) break;

        if (bid == 0 && tid < 16) {     // zero next step's obj accumulators
            st_ag(&quad[pp*16 + tid], 0.0);
            st_ag(&lin[pp*16 + tid],  0.0);
        }

        // stage coef -> LDS
        #pragma unroll
        for (int j = 0; j < 4; ++j)
            s_coef[tid + 256*j] = ld_ag(&coef[p*(BATCHES*FDIM) + batch*FDIM + tid + 256*j]);
        __syncthreads();

        // pred = P coef  (own rows), ratio min
        {
            const int wave = tid >> 6, lane = tid & 63;
            double c[16];
            #pragma unroll
            for (int j = 0; j < 4; ++j) {
                int f = 4*(lane + 64*j);
                c[4*j+0] = s_coef[f+0]; c[4*j+1] = s_coef[f+1];
                c[4*j+2] = s_coef[f+2]; c[4*j+3] = s_coef[f+3];
            }
            double wmin = 1e300;
            for (int i = 0; i < ROWS_PER_BLK/4; ++i) {
                int r  = wave * (ROWS_PER_BLK/4) + i;
                int gr = row_base + r;
                const float4* Pr = (const float4*)(proj + (size_t)gr * FDIM);
                double dot = 0.0;
                #pragma unroll
                for (int j = 0; j < 4; ++j) {
                    float4 pv = Pr[lane + 64*j];
                    dot += (double)pv.x*c[4*j+0] + (double)pv.y*c[4*j+1]
                         + (double)pv.z*c[4*j+2] + (double)pv.w*c[4*j+3];
                }
                for (int off = 32; off > 0; off >>= 1)
                    dot += __shfl_down(dot, off, 64);
                if (lane == 0) {
                    s_pred[r] = dot;
                    st_ag(&pred[gr], dot);
                    if (dot < 0.0) wmin = fmin(wmin, s_x[r] / (-dot));
                }
            }
            if (lane == 0)
                atomicMin(&minr[p*16 + batch], (unsigned long long)__double_as_longlong(wmin));
        }
        grid_barrier(bar, ++g, tid);
    }
}

extern "C" void kernel_launch(void* const* d_in, const int* in_sizes, int n_in,
                              void* d_out, int out_size, void* d_ws, size_t ws_size,
                              hipStream_t stream) {
    const float* x_start      = (const float*)d_in[0];
    const float* rhs          = (const float*)d_in[1];
    const float* proj         = (const float*)d_in[2];
    const float* q            = (const float*)d_in[3];
    const float* obj_solution = (const float*)d_in[4];
    const int*   edge_index   = (const int*)d_in[5];
    const float* edge_weight  = (const float*)d_in[6];
    float* out = (float*)d_out;
    void* ws   = d_ws;

    // zero the barrier cells (arrive, gen) — ws is poisoned 0xAA each launch
    hipMemsetAsync((char*)d_ws + (size_t)WS_BAR * 8, 0, 16, stream);

    void* args[] = { (void*)&x_start, (void*)&rhs, (void*)&proj, (void*)&q,
                     (void*)&obj_solution, (void*)&edge_index, (void*)&edge_weight,
                     (void*)&out, (void*)&ws };
    hipLaunchCooperativeKernel((void*)GradSolver_58102317580919_kernel,
                               dim3(NBLK), dim3(NTHR), args, 0, stream);
}